// Round 4
// baseline (95.967 us; speedup 1.0000x reference)
//
#include <hip/hip_runtime.h>
#include <hip/hip_bf16.h>
#include <stdint.h>

// ---- types -----------------------------------------------------------------
typedef __bf16 bf16x8 __attribute__((ext_vector_type(8)));
typedef float  f32x4  __attribute__((ext_vector_type(4)));
typedef __attribute__((address_space(1))) const void* gptr_t;
typedef __attribute__((address_space(3))) void*       sptr_t;

#define B_ROWS 8192
#define C_CLS  1000
#define C_PAD  1024
#define P_DIM  512
#define EPS    1e-10f

// ---- workspace layout (bytes) ----------------------------------------------
// [0,            1048576)  means_bf16  [1024][512] bf16  (rows >=1000 zeroed)
// [1048576,      1052672)  m_sq        [1024] f32
// [1052672,      9441280)  x_bf16      [8192][512] bf16  (UNNORMALIZED x)
// [9441280,      9506816)  rw          [8192] float2 {2*s_r, x_sq}
#define WS_MEANS_BF 0
#define WS_MSQ      1048576
#define WS_X_BF     1052672
#define WS_RW       9441280

__device__ __forceinline__ float dot8(float4 a, float4 b) {
    return a.x * a.x + a.y * a.y + a.z * a.z + a.w * a.w
         + b.x * b.x + b.y * b.y + b.z * b.z + b.w * b.w;
}

// ---- kernel 1 (fused prep): blocks 0..2047 -> x rows; 2048..2303 -> means ---
// RESCALE TRICK: x is converted to bf16 UNNORMALIZED (store does not wait on
// the reduction chain); per-row (2*s_r, x_sq) goes to a side table and the
// GEMM epilogue applies out = 2*s_r*cross - x_sq - m_sq. Numerically
// equivalent: cross(s_r*x, mu) == s_r*cross(x, mu), s_r applied in f32.
__global__ __launch_bounds__(256) void prep_k(const float* __restrict__ x,
                                              const float* __restrict__ means,
                                              __hip_bfloat16* __restrict__ means_bf,
                                              float* __restrict__ m_sq,
                                              __hip_bfloat16* __restrict__ x_bf,
                                              float2* __restrict__ rw) {
    const int w = threadIdx.x >> 6;
    const int l = threadIdx.x & 63;
    const int bid = blockIdx.x;

    if (bid < B_ROWS / 4) {
        // ---- x row: one wave per row
        const int row = bid * 4 + w;
        const float4* xr = (const float4*)(x + (size_t)row * P_DIM);
        float4 a = xr[l * 2];
        float4 b = xr[l * 2 + 1];
        // store bf16(x) immediately -- independent of the reduction below
        alignas(16) __hip_bfloat16 tmp[8];
        tmp[0] = __float2bfloat16(a.x); tmp[1] = __float2bfloat16(a.y);
        tmp[2] = __float2bfloat16(a.z); tmp[3] = __float2bfloat16(a.w);
        tmp[4] = __float2bfloat16(b.x); tmp[5] = __float2bfloat16(b.y);
        tmp[6] = __float2bfloat16(b.z); tmp[7] = __float2bfloat16(b.w);
        *(uint4*)(x_bf + (size_t)row * P_DIM + l * 8) = *(const uint4*)tmp;
        // reductions: ||x_row||^2 and ||means[0]||^2 (2 KB, L2-hot)
        const float4* m0 = (const float4*)means;
        float4 ma = m0[l * 2];
        float4 mb = m0[l * 2 + 1];
        float ms = dot8(ma, mb);
        float s  = dot8(a, b);
        #pragma unroll
        for (int off = 32; off > 0; off >>= 1) {
            ms += __shfl_down(ms, off);
            s  += __shfl_down(s, off);
        }
        if (l == 0) {
            float scale = sqrtf(ms);           // ||means[0]||
            float norm  = sqrtf(s);
            float sr    = scale / (norm + EPS);
            float sn    = sr * norm;           // ||xn|| as the reference computes it
            rw[row] = make_float2(2.0f * sr, sn * sn);
        }
    } else {
        // ---- means row: one wave per class (padded to 1024)
        const int c = (bid - B_ROWS / 4) * 4 + w;
        if (c < C_CLS) {
            const float4* mr = (const float4*)(means + (size_t)c * P_DIM);
            float4 a = mr[l * 2];
            float4 b = mr[l * 2 + 1];
            float s = dot8(a, b);
            alignas(16) __hip_bfloat16 tmp[8];
            tmp[0] = __float2bfloat16(a.x); tmp[1] = __float2bfloat16(a.y);
            tmp[2] = __float2bfloat16(a.z); tmp[3] = __float2bfloat16(a.w);
            tmp[4] = __float2bfloat16(b.x); tmp[5] = __float2bfloat16(b.y);
            tmp[6] = __float2bfloat16(b.z); tmp[7] = __float2bfloat16(b.w);
            *(uint4*)(means_bf + (size_t)c * P_DIM + l * 8) = *(const uint4*)tmp;
            #pragma unroll
            for (int off = 32; off > 0; off >>= 1) s += __shfl_down(s, off);
            if (l == 0) m_sq[c] = s;
        } else {
            uint4 z = {0u, 0u, 0u, 0u};
            *(uint4*)(means_bf + (size_t)c * P_DIM + l * 8) = z;
            if (l == 0) m_sq[c] = 0.0f;
        }
    }
}

// ---- kernel 2: logits = 2*s_r*(x_bf @ means^T) - x_sq - m_sq ---------------
// 64x128 block tile, BK=32, grid 128x8 = 1024 blocks (4 blocks/CU, 16 waves/CU).
// 4 waves; wave w computes all 64 rows x cols [w*32, w*32+32) via 4x2 mfma
// 16x16x32 (32 acc VGPRs). LDS: A[64][32] @0 (4 KB), B[128][32] @4096 (8 KB).
// Row stride 64 B (conflict-free b128 reads); one K=32 mfma step per tile.
__global__ __launch_bounds__(256, 4) void gemm_k(const __hip_bfloat16* __restrict__ A,   // x_bf [8192][512]
                                                 const __hip_bfloat16* __restrict__ B,   // means[1024][512]
                                                 const float2* __restrict__ rw,          // {2*s_r, x_sq}
                                                 const float* __restrict__ m_sq,
                                                 float* __restrict__ out) {
    __shared__ alignas(16) char lds[12288];
    const int t   = threadIdx.x;
    const int w   = t >> 6;         // wave 0..3
    const int l   = t & 63;
    const int q   = l >> 4;         // quad 0..3
    const int m16 = l & 15;

    const int brow = blockIdx.y;    // 0..127 (64-row tiles)
    const int bcol = blockIdx.x;    // 0..7   (128-col tiles)

    f32x4 acc[4][2];
    #pragma unroll
    for (int i = 0; i < 4; ++i)
        #pragma unroll
        for (int j = 0; j < 2; ++j) {
            f32x4 z = {0.f, 0.f, 0.f, 0.f};
            acc[i][j] = z;
        }

    const char* Abase = (const char*)A + (size_t)(brow * 64)  * (P_DIM * 2);
    const char* Bbase = (const char*)B + (size_t)(bcol * 128) * (P_DIM * 2);

    for (int k0 = 0; k0 < P_DIM; k0 += 32) {
        // ---- stage 12 KB: A tile 4 KB (round 0) + B tile 8 KB (rounds 1,2).
        // Wave-uniform LDS base (wbase); HW adds lane*16.
        #pragma unroll
        for (int r = 0; r < 3; ++r) {
            const int wbase = r * 4096 + w * 1024;   // wave-uniform
            const int o     = wbase + l * 16;
            const char* g;
            if (r == 0) {  // A region: o in [0,4096), row = o>>6
                g = Abase + (size_t)(o >> 6) * (P_DIM * 2) + k0 * 2 + (o & 63);
            } else {       // B region: o' = o-4096 in [0,8192), row = o'>>6
                const int o2 = o - 4096;
                g = Bbase + (size_t)(o2 >> 6) * (P_DIM * 2) + k0 * 2 + (o2 & 63);
            }
            __builtin_amdgcn_global_load_lds((gptr_t)g, (sptr_t)(lds + wbase), 16, 0, 0);
        }
        __syncthreads();

        // ---- one K=32 mfma step over the staged tile
        bf16x8 af[4], bfr[2];
        #pragma unroll
        for (int i = 0; i < 4; ++i) {
            const int m = i * 16 + m16;
            af[i] = *(const bf16x8*)(lds + m * 64 + q * 16);
        }
        #pragma unroll
        for (int j = 0; j < 2; ++j) {
            const int n = w * 32 + j * 16 + m16;
            bfr[j] = *(const bf16x8*)(lds + 4096 + n * 64 + q * 16);
        }
        #pragma unroll
        for (int i = 0; i < 4; ++i)
            #pragma unroll
            for (int j = 0; j < 2; ++j)
                acc[i][j] = __builtin_amdgcn_mfma_f32_16x16x32_bf16(af[i], bfr[j], acc[i][j], 0, 0, 0);
        __syncthreads();
    }

    // ---- epilogue: out = fma(2*s_r, cross, -(x_sq + m_sq))
    // C/D layout: col = lane&15, row = quad*4 + reg [verified m89/m91 + R2/R3 pass]
    const int rowbase = brow * 64;
    const int colbase = bcol * 128 + w * 32;
    float msq[2];
    #pragma unroll
    for (int j = 0; j < 2; ++j) {
        const int col = colbase + j * 16 + m16;
        msq[j] = (col < C_CLS) ? m_sq[col] : 0.0f;
    }
    #pragma unroll
    for (int i = 0; i < 4; ++i) {
        #pragma unroll
        for (int reg = 0; reg < 4; ++reg) {
            const int row = rowbase + i * 16 + q * 4 + reg;
            const float2 r2 = rw[row];          // {2*s_r, x_sq}
            #pragma unroll
            for (int j = 0; j < 2; ++j) {
                const int col = colbase + j * 16 + m16;
                if (col < C_CLS) {
                    out[(size_t)row * C_CLS + col] = fmaf(r2.x, acc[i][j][reg], -(r2.y + msq[j]));
                }
            }
        }
    }
}

// ---- launch ----------------------------------------------------------------
extern "C" void kernel_launch(void* const* d_in, const int* in_sizes, int n_in,
                              void* d_out, int out_size, void* d_ws, size_t ws_size,
                              hipStream_t stream) {
    const float* x     = (const float*)d_in[0];   // [8192][512]
    const float* means = (const float*)d_in[1];   // [1000][512]
    float* out = (float*)d_out;                   // [8192][1000]
    char* ws = (char*)d_ws;

    __hip_bfloat16* means_bf = (__hip_bfloat16*)(ws + WS_MEANS_BF);
    float*          m_sq     = (float*)(ws + WS_MSQ);
    __hip_bfloat16* x_bf     = (__hip_bfloat16*)(ws + WS_X_BF);
    float2*         rw       = (float2*)(ws + WS_RW);

    prep_k<<<B_ROWS / 4 + C_PAD / 4, 256, 0, stream>>>(x, means, means_bf, m_sq, x_bf, rw);
    gemm_k<<<dim3(C_PAD / 128, B_ROWS / 64), 256, 0, stream>>>(x_bf, means_bf, rw, m_sq, out);
}